// Round 1
// baseline (207.924 us; speedup 1.0000x reference)
//
#include <hip/hip_runtime.h>
#include <math.h>

// SEM_40200893890649: TopK_with_h + mat_GRU_cell + 2-layer GCN (fp32)
// B=32 N=2000 D=128 RNN=640 K=64.  idx = top64 duplicated twice -> exploit:
// gather unique 64x64 A0 / 64x128 ne0, fold duplication into 2x factors,
// duplicate output rows at the end.

namespace {
constexpr int B_ = 32;
constexpr int N_ = 2000;
constexpr int D_ = 128;
constexpr int R_ = 640;

// ---------- workspace layout (float offsets) ----------
constexpr size_t OFF_SCORER = 0;        // [32][128]
constexpr size_t OFF_INVN   = 4096;     // [32]
constexpr size_t OFF_SCORES = 4128;     // [32][2000]
constexpr size_t OFF_TKI    = 68128;    // int [32][64]
constexpr size_t OFF_T0     = 70176;    // [32][64] tanh(score) at topk
constexpr size_t OFF_NE0    = 72224;    // [32][64][128]
constexpr size_t OFF_NE0T   = 334368;   // [32][128][64]
constexpr size_t OFF_A0     = 596512;   // [32][64][64] normalized
constexpr size_t OFF_U      = 727584;   // [32][128][128]
constexpr size_t OFF_R      = 1251872;  // [32][128][128]
constexpr size_t OFF_DW     = 1776160;  // [32][128][128]
constexpr size_t OFF_T1     = 2300448;  // [32][64][128]
constexpr size_t OFF_H1     = 2562592;  // [32][64][128]
constexpr size_t OFF_T2     = 2824736;  // [32][64][128]
// total 3086880 floats = 11.8 MiB

// ---------------- K1: scorer = tanh(ht @ mapper_w^T + b); inv_norm ----------------
__global__ __launch_bounds__(128) void k_scorer(
    const float* __restrict__ ht, const float* __restrict__ mw,
    const float* __restrict__ mb, float* __restrict__ scorer,
    float* __restrict__ invn, float* __restrict__ outScorer) {
  const int b = blockIdx.x, d = threadIdx.x;
  __shared__ float sh[R_];
  for (int j = d; j < R_; j += 128) sh[j] = ht[b * R_ + j];
  __syncthreads();
  const float* w = mw + (size_t)d * R_;
  float acc = 0.f;
  for (int j = 0; j < R_; j += 4) {
    float4 wv = *reinterpret_cast<const float4*>(w + j);
    acc += wv.x * sh[j] + wv.y * sh[j + 1] + wv.z * sh[j + 2] + wv.w * sh[j + 3];
  }
  float s = tanhf(acc + mb[d]);
  scorer[b * D_ + d] = s;
  outScorer[b * D_ + d] = s;
  float ss = s * s;
  #pragma unroll
  for (int o = 32; o > 0; o >>= 1) ss += __shfl_down(ss, o);
  __shared__ float red[2];
  if ((d & 63) == 0) red[d >> 6] = ss;
  __syncthreads();
  if (d == 0) invn[b] = 1.0f / sqrtf(red[0] + red[1]);
}

// ---------------- K2: scores[b][n] = dot(node[b,n,:], scorer[b]) * invn ----------------
__global__ __launch_bounds__(256) void k_scores(
    const float* __restrict__ node, const float* __restrict__ scorer,
    const float* __restrict__ invn, float* __restrict__ scores) {
  const int b = blockIdx.x, t = threadIdx.x;
  __shared__ float sc[D_];
  if (t < D_) sc[t] = scorer[b * D_ + t];
  __syncthreads();
  const int n = blockIdx.y * 64 + (t >> 2);
  if (n >= N_) return;
  const int q = t & 3;
  const float* row = node + ((size_t)b * N_ + n) * D_ + q * 32;
  const float* sq = sc + q * 32;
  float acc = 0.f;
  #pragma unroll
  for (int j = 0; j < 32; j += 4) {
    float4 v = *reinterpret_cast<const float4*>(row + j);
    acc += v.x * sq[j] + v.y * sq[j + 1] + v.z * sq[j + 2] + v.w * sq[j + 3];
  }
  acc += __shfl_xor(acc, 1, 4);
  acc += __shfl_xor(acc, 2, 4);
  if (q == 0) scores[(size_t)b * N_ + n] = acc * invn[b];
}

// ---------------- K3: per-batch top-64 (sorted, stable ties) + softmax stats ----------------
__global__ __launch_bounds__(256) void k_topk(
    const float* __restrict__ scores, int* __restrict__ tki,
    float* __restrict__ t0v, float* __restrict__ outPolicy,
    float* __restrict__ outEntropy) {
  const int b = blockIdx.x, t = threadIdx.x;
  const float* S = scores + (size_t)b * N_;
  float v[8];
  #pragma unroll
  for (int s = 0; s < 8; s++) {
    const int n = t + 256 * s;
    v[s] = (n < N_) ? S[n] : -INFINITY;
  }
  __shared__ float s1[4], s2[4];
  // block max
  float m = v[0];
  #pragma unroll
  for (int s = 1; s < 8; s++) m = fmaxf(m, v[s]);
  #pragma unroll
  for (int o = 32; o > 0; o >>= 1) m = fmaxf(m, __shfl_xor(m, o));
  if ((t & 63) == 0) s1[t >> 6] = m;
  __syncthreads();
  const float M = fmaxf(fmaxf(s1[0], s1[1]), fmaxf(s1[2], s1[3]));
  __syncthreads();
  // sum e^x, sum x e^x
  float se = 0.f, sx = 0.f;
  #pragma unroll
  for (int s = 0; s < 8; s++) {
    if (t + 256 * s < N_) {
      const float x = v[s] - M;
      const float e = expf(x);
      se += e;
      sx += x * e;
    }
  }
  #pragma unroll
  for (int o = 32; o > 0; o >>= 1) {
    se += __shfl_xor(se, o);
    sx += __shfl_xor(sx, o);
  }
  if ((t & 63) == 0) { s1[t >> 6] = se; s2[t >> 6] = sx; }
  __syncthreads();
  const float Ssum = s1[0] + s1[1] + s1[2] + s1[3];
  const float Tsum = s2[0] + s2[1] + s2[2] + s2[3];
  // iterative top-64 extraction (argmax w/ lower-index tie-break = lax.top_k order)
  __shared__ float bv4[4];
  __shared__ int bi4[4];
  __shared__ int winIdx;
  __shared__ float winVal;
  float topsum = 0.f;
  for (int k = 0; k < 64; k++) {
    float bv = v[0];
    int bi = t;
    #pragma unroll
    for (int s = 1; s < 8; s++) {
      const int n = t + 256 * s;
      if (v[s] > bv) { bv = v[s]; bi = n; }
    }
    #pragma unroll
    for (int o = 1; o < 64; o <<= 1) {
      const float ov = __shfl_xor(bv, o);
      const int oi = __shfl_xor(bi, o);
      if (ov > bv || (ov == bv && oi < bi)) { bv = ov; bi = oi; }
    }
    if ((t & 63) == 0) { bv4[t >> 6] = bv; bi4[t >> 6] = bi; }
    __syncthreads();
    if (t == 0) {
      float Bv = bv4[0];
      int Bi = bi4[0];
      #pragma unroll
      for (int w = 1; w < 4; w++)
        if (bv4[w] > Bv || (bv4[w] == Bv && bi4[w] < Bi)) { Bv = bv4[w]; Bi = bi4[w]; }
      tki[b * 64 + k] = Bi;
      t0v[b * 64 + k] = tanhf(Bv);
      winIdx = Bi;
      winVal = Bv;
    }
    __syncthreads();
    if (t == 0) topsum += winVal;
    const int w = winIdx;
    #pragma unroll
    for (int s = 0; s < 8; s++)
      if (w == t + 256 * s) v[s] = -INFINITY;
  }
  if (t == 0) {
    const float logS = logf(Ssum);
    outPolicy[b] = topsum * (1.0f / 64.0f) - M - logS;
    outEntropy[b] = logS - Tsum / Ssum;
  }
}

// ---------------- K4: gather ne0, ne0T, normalized A0 ----------------
__global__ __launch_bounds__(256) void k_gather(
    const float* __restrict__ node, const float* __restrict__ Ahat,
    const int* __restrict__ tki, float* __restrict__ ne0,
    float* __restrict__ ne0T, float* __restrict__ A0) {
  const int b = blockIdx.x, t = threadIdx.x;
  __shared__ int idx[64];
  __shared__ float di[64];
  __shared__ float Ar[64][65];
  __shared__ float lne[64][132];
  if (t < 64) idx[t] = tki[b * 64 + t];
  __syncthreads();
  // ne0 gather (also stage in LDS for transpose)
  {
    const int k = t >> 2, q = t & 3;
    const float* src = node + ((size_t)b * N_ + idx[k]) * D_ + q * 32;
    float* dst = ne0 + ((size_t)b * 64 + k) * D_ + q * 32;
    #pragma unroll
    for (int j = 0; j < 32; j += 4) {
      float4 v = *reinterpret_cast<const float4*>(src + j);
      *reinterpret_cast<float4*>(dst + j) = v;
      *reinterpret_cast<float4*>(&lne[k][q * 32 + j]) = v;
    }
  }
  // A unique-block gather
  {
    const int j = t & 63;
    const int cj = idx[j];
    const int i0 = (t >> 6) * 16;
    const float* Ab = Ahat + (size_t)b * N_ * N_;
    #pragma unroll
    for (int s = 0; s < 16; s++) {
      const int i = i0 + s;
      Ar[i][j] = Ab[(size_t)idx[i] * N_ + cj];
    }
  }
  __syncthreads();
  if (t < 64) {
    float sum = 0.f;
    #pragma unroll
    for (int i = 0; i < 64; i++) sum += Ar[i][t];
    di[t] = 1.0f / sqrtf(2.0f * sum);  // full 128-row colsum = 2x unique
  }
  __syncthreads();
  // normalized A0 write
  {
    const int i = t >> 2, j0 = (t & 3) * 16;
    const float dii = di[i];
    float* dst = A0 + ((size_t)b * 64 + i) * 64;
    #pragma unroll
    for (int j4 = 0; j4 < 16; j4 += 4) {
      float4 o;
      o.x = Ar[i][j0 + j4]     * dii * di[j0 + j4];
      o.y = Ar[i][j0 + j4 + 1] * dii * di[j0 + j4 + 1];
      o.z = Ar[i][j0 + j4 + 2] * dii * di[j0 + j4 + 2];
      o.w = Ar[i][j0 + j4 + 3] * dii * di[j0 + j4 + 3];
      *reinterpret_cast<float4*>(dst + j0 + j4) = o;
    }
  }
  // ne0T write
  {
    const int f = t >> 1, kh = (t & 1) * 32;
    float* dst = ne0T + ((size_t)b * D_ + f) * 64 + kh;
    #pragma unroll
    for (int j = 0; j < 32; j += 4) {
      float4 v;
      v.x = lne[kh + j][f];
      v.y = lne[kh + j + 1][f];
      v.z = lne[kh + j + 2][f];
      v.w = lne[kh + j + 3][f];
      *reinterpret_cast<float4*>(dst + j) = v;
    }
  }
}

// ---------------- GRU gates u, r: sigmoid(W@x + U@P + b) ----------------
// grid (B, 4 col-chunks of 32, 2 gates), block 256 (16x16), thread tile 8x2
__global__ __launch_bounds__(256) void k_gru_ur(
    const float* __restrict__ Wu, const float* __restrict__ Uu, const float* __restrict__ bu,
    const float* __restrict__ Wr, const float* __restrict__ Ur, const float* __restrict__ br,
    const float* __restrict__ ne0T, const float* __restrict__ t0v,
    const float* __restrict__ P, float* __restrict__ u_ws, float* __restrict__ r_ws) {
  const int b = blockIdx.x, c = blockIdx.y, z = blockIdx.z;
  const float* W = z ? Wr : Wu;
  const float* U = z ? Ur : Uu;
  const float* bb = z ? br : bu;
  float* dst = z ? r_ws : u_ws;
  const int t = threadIdx.x, tx = t & 15, ty = t >> 4;
  __shared__ float Wt[16][132], Ut[16][132];
  __shared__ float Xt[16][36], Yt[16][36];
  __shared__ float t0s[32];
  if (t < 32) t0s[t] = t0v[b * 64 + (c & 1) * 32 + t];
  const float* neT = ne0T + (size_t)b * D_ * 64;
  const float* Pb = P + (size_t)b * D_ * D_;
  float acc[8][2] = {};
  for (int f0 = 0; f0 < D_; f0 += 16) {
    __syncthreads();
    #pragma unroll
    for (int rr = 0; rr < 8; rr++) {
      const int i = rr * 16 + ty;
      Wt[tx][i] = W[i * D_ + f0 + tx];
      Ut[tx][i] = U[i * D_ + f0 + tx];
    }
    {
      const int ff = ty, kk = tx * 2;
      const int kq = (c & 1) * 32 + kk;
      Xt[ff][kk]     = neT[(f0 + ff) * 64 + kq] * t0s[kk];
      Xt[ff][kk + 1] = neT[(f0 + ff) * 64 + kq + 1] * t0s[kk + 1];
      const float2 p2 = *reinterpret_cast<const float2*>(Pb + (f0 + ff) * D_ + c * 32 + kk);
      Yt[ff][kk] = p2.x;
      Yt[ff][kk + 1] = p2.y;
    }
    __syncthreads();
    #pragma unroll
    for (int ff = 0; ff < 16; ff++) {
      const float xv0 = Xt[ff][tx * 2], xv1 = Xt[ff][tx * 2 + 1];
      const float yv0 = Yt[ff][tx * 2], yv1 = Yt[ff][tx * 2 + 1];
      const float4 wa = *reinterpret_cast<const float4*>(&Wt[ff][ty * 8]);
      const float4 wb = *reinterpret_cast<const float4*>(&Wt[ff][ty * 8 + 4]);
      const float4 ua = *reinterpret_cast<const float4*>(&Ut[ff][ty * 8]);
      const float4 ub = *reinterpret_cast<const float4*>(&Ut[ff][ty * 8 + 4]);
      const float wv[8] = {wa.x, wa.y, wa.z, wa.w, wb.x, wb.y, wb.z, wb.w};
      const float uv[8] = {ua.x, ua.y, ua.z, ua.w, ub.x, ub.y, ub.z, ub.w};
      #pragma unroll
      for (int r = 0; r < 8; r++) {
        acc[r][0] += wv[r] * xv0 + uv[r] * yv0;
        acc[r][1] += wv[r] * xv1 + uv[r] * yv1;
      }
    }
  }
  #pragma unroll
  for (int r = 0; r < 8; r++) {
    const int i = ty * 8 + r;
    #pragma unroll
    for (int cc = 0; cc < 2; cc++) {
      const int k = c * 32 + tx * 2 + cc;
      const float zz = acc[r][cc] + bb[i * D_ + k];
      dst[((size_t)b * D_ + i) * D_ + k] = 1.f / (1.f + expf(-zz));
    }
  }
}

// ---------------- GRU htilda + Dw: tanh(Wh@x + Uh@(r*P) + bh); Dw=(1-u)P+u*ht ----------------
__global__ __launch_bounds__(256) void k_gru_h(
    const float* __restrict__ Wh, const float* __restrict__ Uh, const float* __restrict__ bh,
    const float* __restrict__ ne0T, const float* __restrict__ t0v,
    const float* __restrict__ P, const float* __restrict__ u_ws,
    const float* __restrict__ r_ws, float* __restrict__ Dw) {
  const int b = blockIdx.x, c = blockIdx.y;
  const int t = threadIdx.x, tx = t & 15, ty = t >> 4;
  __shared__ float Wt[16][132], Ut[16][132];
  __shared__ float Xt[16][36], Yt[16][36];
  __shared__ float t0s[32];
  if (t < 32) t0s[t] = t0v[b * 64 + (c & 1) * 32 + t];
  const float* neT = ne0T + (size_t)b * D_ * 64;
  const float* Pb = P + (size_t)b * D_ * D_;
  const float* rb = r_ws + (size_t)b * D_ * D_;
  float acc[8][2] = {};
  for (int f0 = 0; f0 < D_; f0 += 16) {
    __syncthreads();
    #pragma unroll
    for (int rr = 0; rr < 8; rr++) {
      const int i = rr * 16 + ty;
      Wt[tx][i] = Wh[i * D_ + f0 + tx];
      Ut[tx][i] = Uh[i * D_ + f0 + tx];
    }
    {
      const int ff = ty, kk = tx * 2;
      const int kq = (c & 1) * 32 + kk;
      Xt[ff][kk]     = neT[(f0 + ff) * 64 + kq] * t0s[kk];
      Xt[ff][kk + 1] = neT[(f0 + ff) * 64 + kq + 1] * t0s[kk + 1];
      const float2 p2 = *reinterpret_cast<const float2*>(Pb + (f0 + ff) * D_ + c * 32 + kk);
      const float2 r2 = *reinterpret_cast<const float2*>(rb + (f0 + ff) * D_ + c * 32 + kk);
      Yt[ff][kk] = p2.x * r2.x;
      Yt[ff][kk + 1] = p2.y * r2.y;
    }
    __syncthreads();
    #pragma unroll
    for (int ff = 0; ff < 16; ff++) {
      const float xv0 = Xt[ff][tx * 2], xv1 = Xt[ff][tx * 2 + 1];
      const float yv0 = Yt[ff][tx * 2], yv1 = Yt[ff][tx * 2 + 1];
      const float4 wa = *reinterpret_cast<const float4*>(&Wt[ff][ty * 8]);
      const float4 wb = *reinterpret_cast<const float4*>(&Wt[ff][ty * 8 + 4]);
      const float4 ua = *reinterpret_cast<const float4*>(&Ut[ff][ty * 8]);
      const float4 ub = *reinterpret_cast<const float4*>(&Ut[ff][ty * 8 + 4]);
      const float wv[8] = {wa.x, wa.y, wa.z, wa.w, wb.x, wb.y, wb.z, wb.w};
      const float uv[8] = {ua.x, ua.y, ua.z, ua.w, ub.x, ub.y, ub.z, ub.w};
      #pragma unroll
      for (int r = 0; r < 8; r++) {
        acc[r][0] += wv[r] * xv0 + uv[r] * yv0;
        acc[r][1] += wv[r] * xv1 + uv[r] * yv1;
      }
    }
  }
  #pragma unroll
  for (int r = 0; r < 8; r++) {
    const int i = ty * 8 + r;
    #pragma unroll
    for (int cc = 0; cc < 2; cc++) {
      const int k = c * 32 + tx * 2 + cc;
      const size_t off = ((size_t)b * D_ + i) * D_ + k;
      const float zz = acc[r][cc] + bh[i * D_ + k];
      const float hh = tanhf(zz);
      const float uu = u_ws[off];
      const float pp = Pb[i * D_ + k];
      Dw[off] = (1.f - uu) * pp + uu * hh;
    }
  }
}

// ---------------- GCN chain GEMMs: C(64x128) = epi(Asrc(64xKK) @ Bsrc(KKx128)) ----------------
// MODE 0: t1 = ne0@Dw   (KK=128)
// MODE 1: h1 = relu(2*A0@t1) (KK=64)
// MODE 2: t2 = h1@static_w (KK=128)
// MODE 3: h2 = relu(2*A0@t2); out = 0.5*(h1+h2), rows duplicated (KK=64)
template <int MODE>
__global__ __launch_bounds__(256) void k_gcn(
    const float* __restrict__ Asrc, const float* __restrict__ Bsrc,
    const float* __restrict__ h1_ws, float* __restrict__ out,
    int lda, int ldb, int astride, int bstride) {
  constexpr int KK = (MODE == 0 || MODE == 2) ? 128 : 64;
  const int b = blockIdx.x, c = blockIdx.y;
  const int t = threadIdx.x, tx = t & 15, ty = t >> 4;
  __shared__ float At[16][68], Bt[16][68];
  const float* A = Asrc + (size_t)b * astride;
  const float* Bm = Bsrc + (size_t)b * bstride;
  float acc[4][4] = {};
  for (int f0 = 0; f0 < KK; f0 += 16) {
    __syncthreads();
    #pragma unroll
    for (int rr = 0; rr < 4; rr++) {
      const int i = rr * 16 + ty;
      At[tx][i] = A[i * lda + f0 + tx];
    }
    {
      const int ff = ty, k4 = tx * 4;
      const float4 bv = *reinterpret_cast<const float4*>(Bm + (f0 + ff) * ldb + c * 64 + k4);
      *reinterpret_cast<float4*>(&Bt[ff][k4]) = bv;
    }
    __syncthreads();
    #pragma unroll
    for (int ff = 0; ff < 16; ff++) {
      const float4 av = *reinterpret_cast<const float4*>(&At[ff][ty * 4]);
      const float4 bv = *reinterpret_cast<const float4*>(&Bt[ff][tx * 4]);
      const float a_[4] = {av.x, av.y, av.z, av.w};
      const float b_[4] = {bv.x, bv.y, bv.z, bv.w};
      #pragma unroll
      for (int r = 0; r < 4; r++)
        #pragma unroll
        for (int cc = 0; cc < 4; cc++) acc[r][cc] += a_[r] * b_[cc];
    }
  }
  #pragma unroll
  for (int r = 0; r < 4; r++) {
    const int i = ty * 4 + r;
    const int k = c * 64 + tx * 4;
    if constexpr (MODE == 0 || MODE == 2) {
      float4 o = {acc[r][0], acc[r][1], acc[r][2], acc[r][3]};
      *reinterpret_cast<float4*>(out + ((size_t)b * 64 + i) * D_ + k) = o;
    } else if constexpr (MODE == 1) {
      float4 o = {fmaxf(2.f * acc[r][0], 0.f), fmaxf(2.f * acc[r][1], 0.f),
                  fmaxf(2.f * acc[r][2], 0.f), fmaxf(2.f * acc[r][3], 0.f)};
      *reinterpret_cast<float4*>(out + ((size_t)b * 64 + i) * D_ + k) = o;
    } else {
      const float4 h1v = *reinterpret_cast<const float4*>(h1_ws + ((size_t)b * 64 + i) * D_ + k);
      float4 o;
      o.x = 0.5f * (h1v.x + fmaxf(2.f * acc[r][0], 0.f));
      o.y = 0.5f * (h1v.y + fmaxf(2.f * acc[r][1], 0.f));
      o.z = 0.5f * (h1v.z + fmaxf(2.f * acc[r][2], 0.f));
      o.w = 0.5f * (h1v.w + fmaxf(2.f * acc[r][3], 0.f));
      *reinterpret_cast<float4*>(out + ((size_t)b * D_ + i) * D_ + k) = o;
      *reinterpret_cast<float4*>(out + ((size_t)b * D_ + i + 64) * D_ + k) = o;
    }
  }
}

}  // namespace

extern "C" void kernel_launch(void* const* d_in, const int* in_sizes, int n_in,
                              void* d_out, int out_size, void* d_ws, size_t ws_size,
                              hipStream_t stream) {
  (void)in_sizes; (void)n_in; (void)out_size; (void)ws_size;
  const float* Ahat = (const float*)d_in[0];
  const float* node = (const float*)d_in[1];
  const float* ht   = (const float*)d_in[2];
  const float* prevD= (const float*)d_in[3];
  const float* mw   = (const float*)d_in[4];
  const float* mb   = (const float*)d_in[5];
  const float* Wu   = (const float*)d_in[6];
  const float* Uu   = (const float*)d_in[7];
  const float* bu   = (const float*)d_in[8];
  const float* Wr   = (const float*)d_in[9];
  const float* Ur   = (const float*)d_in[10];
  const float* br   = (const float*)d_in[11];
  const float* Wh   = (const float*)d_in[12];
  const float* Uh   = (const float*)d_in[13];
  const float* bh   = (const float*)d_in[14];
  const float* sw   = (const float*)d_in[15];

  float* out = (float*)d_out;
  float* outPolicy  = out + (size_t)B_ * D_ * D_;          // 524288
  float* outScorer  = outPolicy + B_;                       // 524320
  float* outEntropy = outScorer + (size_t)B_ * D_;          // 528416

  float* ws = (float*)d_ws;
  float* scorer = ws + OFF_SCORER;
  float* invn   = ws + OFF_INVN;
  float* scores = ws + OFF_SCORES;
  int*   tki    = (int*)(ws + OFF_TKI);
  float* t0v    = ws + OFF_T0;
  float* ne0    = ws + OFF_NE0;
  float* ne0T   = ws + OFF_NE0T;
  float* A0     = ws + OFF_A0;
  float* u_ws   = ws + OFF_U;
  float* r_ws   = ws + OFF_R;
  float* Dw     = ws + OFF_DW;
  float* t1     = ws + OFF_T1;
  float* h1     = ws + OFF_H1;
  float* t2     = ws + OFF_T2;

  k_scorer<<<B_, 128, 0, stream>>>(ht, mw, mb, scorer, invn, outScorer);
  k_scores<<<dim3(B_, 32), 256, 0, stream>>>(node, scorer, invn, scores);
  k_topk<<<B_, 256, 0, stream>>>(scores, tki, t0v, outPolicy, outEntropy);
  k_gather<<<B_, 256, 0, stream>>>(node, Ahat, tki, ne0, ne0T, A0);
  k_gru_ur<<<dim3(B_, 4, 2), 256, 0, stream>>>(Wu, Uu, bu, Wr, Ur, br, ne0T, t0v,
                                               prevD, u_ws, r_ws);
  k_gru_h<<<dim3(B_, 4), 256, 0, stream>>>(Wh, Uh, bh, ne0T, t0v, prevD, u_ws, r_ws, Dw);
  // GCN chain on unique 64-row blocks
  k_gcn<0><<<dim3(B_, 2), 256, 0, stream>>>(ne0, Dw, nullptr, t1, 128, 128, 64 * 128, 128 * 128);
  k_gcn<1><<<dim3(B_, 2), 256, 0, stream>>>(A0, t1, nullptr, h1, 64, 128, 64 * 64, 64 * 128);
  k_gcn<2><<<dim3(B_, 2), 256, 0, stream>>>(h1, sw, nullptr, t2, 128, 128, 64 * 128, 0);
  k_gcn<3><<<dim3(B_, 2), 256, 0, stream>>>(A0, t2, h1, out, 64, 128, 64 * 64, 64 * 128);
}